// Round 1
// baseline (1471.348 us; speedup 1.0000x reference)
//
#include <hip/hip_runtime.h>
#include <cstddef>
#include <cstdint>

#define N_ROWS 8192
#define IN_DIM 512
#define HID    256
#define OUT_DIM 64

// ---------------------------------------------------------------------------
// GEMM: C[M,Nc] = (A[M,K] @ B[Nc,K]^T + bias), optional PReLU epilogue.
// BM=BN=64, BK=32, 256 threads, 4x4 micro-tile per thread.
// ---------------------------------------------------------------------------
__global__ __launch_bounds__(256) void gemm_bt(
    const float* __restrict__ A, const float* __restrict__ B,
    const float* __restrict__ bias, const float* __restrict__ prelu_a,
    float* __restrict__ C, int M, int Nc, int K, int do_prelu)
{
    __shared__ float As[32][68];
    __shared__ float Bs[32][68];
    const int t  = threadIdx.x;
    const int m0 = blockIdx.x * 64;
    const int n0 = blockIdx.y * 64;
    const int tx = t & 15, ty = t >> 4;
    float acc[4][4] = {};

    for (int k0 = 0; k0 < K; k0 += 32) {
        #pragma unroll
        for (int r = 0; r < 2; ++r) {
            int f4 = t + r * 256;          // 512 float4 per tile
            int row = f4 >> 3, q = f4 & 7; // 8 float4 per row of 32 k's
            float4 va = *(const float4*)&A[(size_t)(m0 + row) * K + k0 + q * 4];
            As[q*4+0][row] = va.x; As[q*4+1][row] = va.y;
            As[q*4+2][row] = va.z; As[q*4+3][row] = va.w;
            float4 vb = *(const float4*)&B[(size_t)(n0 + row) * K + k0 + q * 4];
            Bs[q*4+0][row] = vb.x; Bs[q*4+1][row] = vb.y;
            Bs[q*4+2][row] = vb.z; Bs[q*4+3][row] = vb.w;
        }
        __syncthreads();
        #pragma unroll
        for (int kk = 0; kk < 32; ++kk) {
            float4 av = *(const float4*)&As[kk][ty * 4];
            float4 bv = *(const float4*)&Bs[kk][tx * 4];
            float a[4] = {av.x, av.y, av.z, av.w};
            float b[4] = {bv.x, bv.y, bv.z, bv.w};
            #pragma unroll
            for (int ii = 0; ii < 4; ++ii)
                #pragma unroll
                for (int jj = 0; jj < 4; ++jj)
                    acc[ii][jj] = fmaf(a[ii], b[jj], acc[ii][jj]);
        }
        __syncthreads();
    }

    const float alpha = do_prelu ? *prelu_a : 0.0f;
    #pragma unroll
    for (int ii = 0; ii < 4; ++ii) {
        int row = m0 + ty * 4 + ii;
        #pragma unroll
        for (int jj = 0; jj < 4; ++jj) {
            int col = n0 + tx * 4 + jj;
            float v = acc[ii][jj] + bias[col];
            if (do_prelu) v = v > 0.0f ? v : alpha * v;
            C[(size_t)row * Nc + col] = v;
        }
    }
}

// ---------------------------------------------------------------------------
// Row softmax of emb (64 cols == 64 lanes), then L2-normalize -> u.
// re_ij = (s_i . s_j)/max(sqrt(|s_i|^2 |s_j|^2), 1e-9) == u_i . u_j
// (norms >= 1/8, so the eps clamp never binds).
// ---------------------------------------------------------------------------
__global__ __launch_bounds__(256) void softmax_u(
    const float* __restrict__ emb, float* __restrict__ u)
{
    const int wave = threadIdx.x >> 6, lane = threadIdx.x & 63;
    const int row = blockIdx.x * 4 + wave;
    float e = emb[(size_t)row * OUT_DIM + lane];
    float mx = e;
    #pragma unroll
    for (int m = 32; m; m >>= 1) mx = fmaxf(mx, __shfl_xor(mx, m));
    float ex = expf(e - mx);
    float sm = ex;
    #pragma unroll
    for (int m = 32; m; m >>= 1) sm += __shfl_xor(sm, m);
    float s = ex / sm;
    float n2 = s * s;
    #pragma unroll
    for (int m = 32; m; m >>= 1) n2 += __shfl_xor(n2, m);
    u[(size_t)row * OUT_DIM + lane] = s * __frsqrt_rn(n2) * n2 == n2 ? s / sqrtf(n2) : s / sqrtf(n2);
}

// ---------------------------------------------------------------------------
// Pass A: global sum & max of lr = 0.5*lre + 0.5*re (diag of re zeroed).
// 32 rows/block, 8 lanes cooperate per row (8-elem dot slices + shfl reduce).
// ---------------------------------------------------------------------------
__global__ __launch_bounds__(256) void pass_a(
    const float* __restrict__ u, const float* __restrict__ lre,
    float* __restrict__ psum_out, float* __restrict__ pmax_out, int jlen)
{
    __shared__ float uT[64][64];
    const int t = threadIdx.x;
    const int s = t & 7;           // dot slice
    const int il = t >> 3;         // local row 0..31
    const int i = blockIdx.x * 32 + il;
    float ui[8];
    #pragma unroll
    for (int e = 0; e < 8; ++e) ui[e] = u[(size_t)i * 64 + s * 8 + e];

    const int j0 = blockIdx.y * jlen;
    float psum = 0.0f, pmax = -1e30f;

    for (int jt = 0; jt < jlen; jt += 64) {
        __syncthreads();
        #pragma unroll
        for (int r = 0; r < 4; ++r) {
            int f4 = t + r * 256;
            int row = f4 >> 4, q = f4 & 15;
            *(float4*)&uT[row][q * 4] =
                *(const float4*)&u[(size_t)(j0 + jt + row) * 64 + q * 4];
        }
        __syncthreads();
        const float* lrow = &lre[(size_t)i * N_ROWS + j0 + jt];
        #pragma unroll 8
        for (int jj = 0; jj < 64; ++jj) {
            float d = 0.0f;
            #pragma unroll
            for (int e = 0; e < 8; ++e) d = fmaf(ui[e], uT[jj][s * 8 + e], d);
            d += __shfl_xor(d, 1); d += __shfl_xor(d, 2); d += __shfl_xor(d, 4);
            int j = j0 + jt + jj;
            float re = (i == j) ? 0.0f : d;
            float lr = 0.5f * lrow[jj] + 0.5f * re;
            if (s == 0) psum += lr;
            pmax = fmaxf(pmax, lr);
        }
    }
    // block reduce
    #pragma unroll
    for (int m = 1; m < 64; m <<= 1) {
        psum += __shfl_xor(psum, m);
        pmax = fmaxf(pmax, __shfl_xor(pmax, m));
    }
    __shared__ float rs[4], rm[4];
    if ((t & 63) == 0) { rs[t >> 6] = psum; rm[t >> 6] = pmax; }
    __syncthreads();
    if (t == 0) {
        float S = (rs[0] + rs[1]) + (rs[2] + rs[3]);
        float M = fmaxf(fmaxf(rm[0], rm[1]), fmaxf(rm[2], rm[3]));
        int bid = blockIdx.x * gridDim.y + blockIdx.y;
        psum_out[bid] = S; pmax_out[bid] = M;
    }
}

__global__ __launch_bounds__(256) void reduce_stats(
    const float* __restrict__ psum, const float* __restrict__ pmax,
    float* __restrict__ sc, int npart)
{
    const int t = threadIdx.x;
    float s = 0.0f, m = -1e30f;
    for (int k = t; k < npart; k += 256) { s += psum[k]; m = fmaxf(m, pmax[k]); }
    #pragma unroll
    for (int w = 1; w < 64; w <<= 1) { s += __shfl_xor(s, w); m = fmaxf(m, __shfl_xor(m, w)); }
    __shared__ float rs[4], rm[4];
    if ((t & 63) == 0) { rs[t >> 6] = s; rm[t >> 6] = m; }
    __syncthreads();
    if (t == 0) {
        float S = (rs[0] + rs[1]) + (rs[2] + rs[3]);
        float M = fmaxf(fmaxf(rm[0], rm[1]), fmaxf(rm[2], rm[3]));
        float mean = S / (8192.0f * 8192.0f);
        sc[0] = mean;
        sc[1] = 1.0f / (M - mean);   // 1/pos_diff
        sc[2] = 1.0f / mean;         // neg branch scale
    }
}

// ---------------------------------------------------------------------------
// Pass B: recompute lr, normalize, +I, both prelu branches, accumulate
// S_pos[i,:] += p*emb[j,:], S_neg[i,:] += q*emb[j,:] over the j-chunk.
// ---------------------------------------------------------------------------
__global__ __launch_bounds__(256) void pass_b(
    const float* __restrict__ u, const float* __restrict__ emb,
    const float* __restrict__ lre, const float* __restrict__ sc,
    const float* __restrict__ prelu_a,
    float* __restrict__ Spos, float* __restrict__ Sneg, int jlen)
{
    __shared__ float uT[64][64];
    __shared__ float eT[64][64];
    const int t = threadIdx.x;
    const int s = t & 7;
    const int il = t >> 3;
    const int i = blockIdx.x * 32 + il;
    float ui[8];
    #pragma unroll
    for (int e = 0; e < 8; ++e) ui[e] = u[(size_t)i * 64 + s * 8 + e];

    const float mean = sc[0], ipd = sc[1], im = sc[2];
    const float alpha = *prelu_a;
    float ap[8] = {}, an[8] = {};
    const int j0 = blockIdx.y * jlen;

    for (int jt = 0; jt < jlen; jt += 64) {
        __syncthreads();
        #pragma unroll
        for (int r = 0; r < 4; ++r) {
            int f4 = t + r * 256;
            int row = f4 >> 4, q = f4 & 15;
            *(float4*)&uT[row][q * 4] =
                *(const float4*)&u[(size_t)(j0 + jt + row) * 64 + q * 4];
            *(float4*)&eT[row][q * 4] =
                *(const float4*)&emb[(size_t)(j0 + jt + row) * 64 + q * 4];
        }
        __syncthreads();
        const float* lrow = &lre[(size_t)i * N_ROWS + j0 + jt];
        #pragma unroll 8
        for (int jj = 0; jj < 64; ++jj) {
            float d = 0.0f;
            #pragma unroll
            for (int e = 0; e < 8; ++e) d = fmaf(ui[e], uT[jj][s * 8 + e], d);
            d += __shfl_xor(d, 1); d += __shfl_xor(d, 2); d += __shfl_xor(d, 4);
            int j = j0 + jt + jj;
            float re = (i == j) ? 0.0f : d;
            float lr = 0.5f * lrow[jj] + 0.5f * re;
            float tsh = lr - mean;
            float x = (tsh > 0.0f) ? tsh * ipd : -(lr * im);
            if (i == j) x += 1.0f;
            float p = (x > 0.0f) ? x : alpha * x;      // prelu(x)
            float q = (x < 0.0f) ? -x : -alpha * x;    // prelu(-x)
            #pragma unroll
            for (int e = 0; e < 8; ++e) {
                float eb = eT[jj][s * 8 + e];
                ap[e] = fmaf(p, eb, ap[e]);
                an[e] = fmaf(q, eb, an[e]);
            }
        }
    }
    size_t base = ((size_t)blockIdx.y * N_ROWS + i) * 64 + s * 8;
    #pragma unroll
    for (int e = 0; e < 8; ++e) { Spos[base + e] = ap[e]; Sneg[base + e] = an[e]; }
}

// ---------------------------------------------------------------------------
// Final: reduce j-chunk partials, dual row-softmax, output.
// ---------------------------------------------------------------------------
__global__ __launch_bounds__(256) void final_k(
    const float* __restrict__ Spos, const float* __restrict__ Sneg,
    const float* __restrict__ emb, float* __restrict__ out, int JC)
{
    const int wave = threadIdx.x >> 6, lane = threadIdx.x & 63;
    const int row = blockIdx.x * 4 + wave;
    float sp = 0.0f, sn = 0.0f;
    for (int jc = 0; jc < JC; ++jc) {
        sp += Spos[((size_t)jc * N_ROWS + row) * 64 + lane];
        sn += Sneg[((size_t)jc * N_ROWS + row) * 64 + lane];
    }
    float mx = sp;
    #pragma unroll
    for (int m = 32; m; m >>= 1) mx = fmaxf(mx, __shfl_xor(mx, m));
    float e1 = expf(sp - mx);
    float s1 = e1;
    #pragma unroll
    for (int m = 32; m; m >>= 1) s1 += __shfl_xor(s1, m);
    float pp = e1 / s1;

    float mx2 = sn;
    #pragma unroll
    for (int m = 32; m; m >>= 1) mx2 = fmaxf(mx2, __shfl_xor(mx2, m));
    float e2 = expf(sn - mx2);
    float s2 = e2;
    #pragma unroll
    for (int m = 32; m; m >>= 1) s2 += __shfl_xor(s2, m);
    float pn = e2 / s2;

    size_t idx = (size_t)row * OUT_DIM + lane;
    out[idx] = 0.5f * (pp - pn + emb[idx]);
}

// ---------------------------------------------------------------------------
extern "C" void kernel_launch(void* const* d_in, const int* in_sizes, int n_in,
                              void* d_out, int out_size, void* d_ws, size_t ws_size,
                              hipStream_t stream)
{
    const float* feature = (const float*)d_in[0];
    const float* lre     = (const float*)d_in[1];
    const float* W0      = (const float*)d_in[2];
    const float* b0      = (const float*)d_in[3];
    const float* W1      = (const float*)d_in[4];
    const float* b1      = (const float*)d_in[5];
    const float* prelu_a = (const float*)d_in[6];
    float* out = (float*)d_out;
    float* ws  = (float*)d_ws;

    const size_t NE = (size_t)N_ROWS * OUT_DIM;        // 524288 floats
    float* emb = ws;
    float* u   = ws + NE;
    float* h   = ws + 2 * NE;                          // 8192*256 floats

    auto need_bytes = [&](int jc) -> size_t {
        return (2 * NE + (size_t)N_ROWS * HID + (size_t)2 * jc * NE + 4096 + 16)
               * sizeof(float);
    };
    int JC = 4;
    if (ws_size < need_bytes(4)) JC = (ws_size >= need_bytes(2)) ? 2 : 1;

    float* Spos = h + (size_t)N_ROWS * HID;
    float* Sneg = Spos + (size_t)JC * NE;
    float* psum = Sneg + (size_t)JC * NE;
    float* pmax = psum + 2048;
    float* sc   = pmax + 2048;

    // MLP
    gemm_bt<<<dim3(128, 4), 256, 0, stream>>>(feature, W0, b0, prelu_a, h,
                                              N_ROWS, HID, IN_DIM, 1);
    gemm_bt<<<dim3(128, 1), 256, 0, stream>>>(h, W1, b1, prelu_a, emb,
                                              N_ROWS, OUT_DIM, HID, 0);
    // softmax + normalize
    softmax_u<<<N_ROWS / 4, 256, 0, stream>>>(emb, u);
    // global stats of lr
    pass_a<<<dim3(256, 4), 256, 0, stream>>>(u, lre, psum, pmax, N_ROWS / 4);
    reduce_stats<<<1, 256, 0, stream>>>(psum, pmax, sc, 256 * 4);
    // propagation accumulation
    pass_b<<<dim3(256, JC), 256, 0, stream>>>(u, emb, lre, sc, prelu_a,
                                              Spos, Sneg, N_ROWS / JC);
    // finalize
    final_k<<<N_ROWS / 4, 256, 0, stream>>>(Spos, Sneg, emb, out, JC);
}